// Round 1
// 776.788 us; speedup vs baseline: 1.2164x; 1.2164x over previous
//
#include <hip/hip_runtime.h>
#include <hip/hip_bf16.h>
#include <stdint.h>

using bf16 = __hip_bfloat16;
typedef __attribute__((ext_vector_type(8))) short bf16x8;
typedef __attribute__((ext_vector_type(4))) float f32x4;

union U8 { uint4 u; bf16x8 h; };

static __device__ __forceinline__ float b2f(bf16 v) { return __bfloat162float(v); }
static __device__ __forceinline__ bf16  f2b(float v) { return __float2bfloat16(v); }
static __device__ __forceinline__ float toF(float v) { return v; }
static __device__ __forceinline__ float toF(bf16 v)  { return __bfloat162float(v); }
static __device__ __forceinline__ void stF(float* p, float v) { *p = v; }
static __device__ __forceinline__ void stF(bf16* p,  float v) { *p = f2b(v); }
static __device__ __forceinline__ float bfu(unsigned short x) {
  union { unsigned int i; float f; } z; z.i = ((unsigned int)x) << 16; return z.f;
}

// ---------------- weight convert: w[k][n] fp32 -> wt[n][k] bf16, k zero-padded to Kp ----
__global__ __launch_bounds__(256) void convert_wt_kernel(
    const float* __restrict__ w, bf16* __restrict__ wt, int K, int N, int Kp)
{
  int idx = blockIdx.x * 256 + threadIdx.x;
  if (idx >= N * Kp) return;
  int n = idx / Kp, k = idx % Kp;
  float v = (k < K) ? w[(size_t)k * N + n] : 0.f;
  wt[idx] = f2b(v);
}

// ---------------- bias precompute: bias_f[hh][r][kk] = rpb[rpi[r,kk]*6+hh] --------------
__global__ __launch_bounds__(256) void bias_pre_kernel(
    const int* __restrict__ rpi, const float* __restrict__ rpb, float* __restrict__ bias_f)
{
  int e = blockIdx.x * 256 + threadIdx.x;
  if (e >= 6 * 64 * 144) return;
  int hh = e / 9216, rk = e % 9216;
  bias_f[e] = rpb[rpi[rk] * 6 + hh];
}

// ---------------- LN1 + DWT: x fp32 (2,256,256,180) -> xd bf16 (2,128,128,720) ----------
__global__ __launch_bounds__(256) void ln_dwt_kernel(
    const float* __restrict__ x, const float* __restrict__ w, const float* __restrict__ bia,
    bf16* __restrict__ xd)
{
  __shared__ float nrm[4][180];
  int blk = blockIdx.x;
  int j = blk & 127; int i = (blk >> 7) & 127; int b = blk >> 14;
  int wave = threadIdx.x >> 6, lane = threadIdx.x & 63;
  int ty = wave >> 1, tx = wave & 1;
  size_t tok = (size_t)b * 65536 + (size_t)(2 * i + ty) * 256 + (size_t)(2 * j + tx);
  const float* xp = x + tok * 180;
  float v0 = xp[lane];
  float v1 = xp[lane + 64];
  float v2 = (lane < 52) ? xp[lane + 128] : 0.f;
  float s = v0 + v1 + v2, ss = v0 * v0 + v1 * v1 + v2 * v2;
  #pragma unroll
  for (int m = 32; m; m >>= 1) { s += __shfl_xor(s, m); ss += __shfl_xor(ss, m); }
  float mu = s * (1.f / 180.f);
  float rstd = rsqrtf(ss * (1.f / 180.f) - mu * mu + 1e-5f);
  nrm[wave][lane]      = (v0 - mu) * rstd * w[lane]      + bia[lane];
  nrm[wave][lane + 64] = (v1 - mu) * rstd * w[lane + 64] + bia[lane + 64];
  if (lane < 52)
    nrm[wave][lane + 128] = (v2 - mu) * rstd * w[lane + 128] + bia[lane + 128];
  __syncthreads();
  bf16* op = xd + (size_t)blk * 720;
  for (int o = threadIdx.x; o < 720; o += 256) {
    int g = o / 180, c = o % 180;
    float a = nrm[0][c], bb = nrm[1][c], cc = nrm[2][c], dd = nrm[3][c];
    float r = (g == 0) ? (a + bb + cc + dd)
            : (g == 1) ? (-a - bb + cc + dd)
            : (g == 2) ? (-a + bb - cc + dd)
                       : (a - bb - cc + dd);
    op[o] = f2b(r * 0.5f);
  }
}

// ---------------- plain LN: x1 bf16 (131072,180) -> y bf16 stride 192 (zero-padded) -----
__global__ __launch_bounds__(256) void ln_kernel(
    const bf16* __restrict__ x, const float* __restrict__ w, const float* __restrict__ bia,
    bf16* __restrict__ y)
{
  int wave = threadIdx.x >> 6, lane = threadIdx.x & 63;
  size_t tok = (size_t)blockIdx.x * 4 + wave;
  const bf16* xp = x + tok * 180;
  float v0 = b2f(xp[lane]);
  float v1 = b2f(xp[lane + 64]);
  float v2 = (lane < 52) ? b2f(xp[lane + 128]) : 0.f;
  float s = v0 + v1 + v2, ss = v0 * v0 + v1 * v1 + v2 * v2;
  #pragma unroll
  for (int m = 32; m; m >>= 1) { s += __shfl_xor(s, m); ss += __shfl_xor(ss, m); }
  float mu = s * (1.f / 180.f);
  float rstd = rsqrtf(ss * (1.f / 180.f) - mu * mu + 1e-5f);
  bf16* yp = y + tok * 192;
  yp[lane]      = f2b((v0 - mu) * rstd * w[lane]      + bia[lane]);
  yp[lane + 64] = f2b((v1 - mu) * rstd * w[lane + 64] + bia[lane + 64]);
  if (lane < 52)
    yp[lane + 128] = f2b((v2 - mu) * rstd * w[lane + 128] + bia[lane + 128]);
  else
    yp[lane + 128] = f2b(0.f);
}

// ---------------- MFMA GEMM: out = ep(A@Wt^T + bias [, res]) ----------------------------
template <int EP, typename TRes, typename TOut>
__global__ __launch_bounds__(256) void gemm_mfma(
    const bf16* __restrict__ A, const bf16* __restrict__ Wt,
    const float* __restrict__ bias, const TRes* __restrict__ res,
    TOut* __restrict__ out, int N, int KlimA, int lda, int Kp, int ldout, int ldres)
{
  __shared__ __align__(16) short Al[128 * 32];
  __shared__ __align__(16) short Bl[64 * 32];
  int tid = threadIdx.x;
  int wave = tid >> 6, lane = tid & 63;
  int wy = wave >> 1, wx = wave & 1;
  int m0 = blockIdx.x * 128, n0 = blockIdx.y * 64;

  f32x4 acc[4][2] = {};

  int ar = tid >> 2;
  int ac = (tid & 3) * 8;
  int brow = n0 + ar;
  int browc = (brow < N) ? brow : (N - 1);
  bool bvalid = (brow < N);
  const uint4* ga0 = (const uint4*)(A + (size_t)(m0 + ar) * lda + ac);
  const uint4* ga1 = (const uint4*)(A + (size_t)(m0 + 64 + ar) * lda + ac);
  const uint4* gb  = (const uint4*)(Wt + (size_t)browc * Kp + ac);

  int fm = lane & 15, quad = lane >> 4;
  const short* afp = &Al[(wy * 64 + fm) * 32 + quad * 8];
  const short* bfp = &Bl[(wx * 32 + fm) * 32 + quad * 8];

  for (int k0 = 0; k0 < Kp; k0 += 32) {
    bool avalid = (k0 + ac) < KlimA;
    uint4 za = avalid ? ga0[k0 / 8] : make_uint4(0, 0, 0, 0);
    uint4 zb = avalid ? ga1[k0 / 8] : make_uint4(0, 0, 0, 0);
    uint4 zc = bvalid ? gb[k0 / 8]  : make_uint4(0, 0, 0, 0);
    __syncthreads();
    *(uint4*)&Al[tid * 8]        = za;
    *(uint4*)&Al[2048 + tid * 8] = zb;
    *(uint4*)&Bl[tid * 8]        = zc;
    __syncthreads();

    bf16x8 af0 = *(const bf16x8*)(afp);
    bf16x8 af1 = *(const bf16x8*)(afp + 16 * 32);
    bf16x8 af2 = *(const bf16x8*)(afp + 32 * 32);
    bf16x8 af3 = *(const bf16x8*)(afp + 48 * 32);
    bf16x8 bf0 = *(const bf16x8*)(bfp);
    bf16x8 bf1 = *(const bf16x8*)(bfp + 16 * 32);

    acc[0][0] = __builtin_amdgcn_mfma_f32_16x16x32_bf16(af0, bf0, acc[0][0], 0, 0, 0);
    acc[0][1] = __builtin_amdgcn_mfma_f32_16x16x32_bf16(af0, bf1, acc[0][1], 0, 0, 0);
    acc[1][0] = __builtin_amdgcn_mfma_f32_16x16x32_bf16(af1, bf0, acc[1][0], 0, 0, 0);
    acc[1][1] = __builtin_amdgcn_mfma_f32_16x16x32_bf16(af1, bf1, acc[1][1], 0, 0, 0);
    acc[2][0] = __builtin_amdgcn_mfma_f32_16x16x32_bf16(af2, bf0, acc[2][0], 0, 0, 0);
    acc[2][1] = __builtin_amdgcn_mfma_f32_16x16x32_bf16(af2, bf1, acc[2][1], 0, 0, 0);
    acc[3][0] = __builtin_amdgcn_mfma_f32_16x16x32_bf16(af3, bf0, acc[3][0], 0, 0, 0);
    acc[3][1] = __builtin_amdgcn_mfma_f32_16x16x32_bf16(af3, bf1, acc[3][1], 0, 0, 0);
  }

  #pragma unroll
  for (int nt = 0; nt < 2; nt++) {
    int col = n0 + wx * 32 + nt * 16 + fm;
    if (col >= N) continue;
    float bv = bias[col];
    #pragma unroll
    for (int mt = 0; mt < 4; mt++) {
      int row0 = m0 + wy * 64 + mt * 16 + quad * 4;
      #pragma unroll
      for (int r = 0; r < 4; r++) {
        int row = row0 + r;
        float v = acc[mt][nt][r] + bv;
        if constexpr (EP == 1) v += toF(res[(size_t)row * ldres + col]);
        if constexpr (EP == 2) v = 0.5f * v * (1.f + erff(v * 0.70710678118654752f));
        stF(&out[(size_t)row * ldout + col], v);
      }
    }
  }
}

// ---------------- MFMA attention: one block per (window, head) --------------------------
// q,k: bf16 stride 180; v: bf16 stride 720; xw out bf16 stride 720; bias_f: [6][64][144]
// New structure: token-offset table; Q/K fragments loaded direct from global;
// V transposed into LDS via uint4 loads + XOR-bit-4 swizzled short writes.
__global__ __launch_bounds__(256) void attn_kernel(
    const bf16* __restrict__ q, const bf16* __restrict__ k, const bf16* __restrict__ v,
    const float* __restrict__ bias_f, bf16* __restrict__ xw)
{
  __shared__ short tokl[160];                       // 144 used; -1 = OOB
  __shared__ __align__(16) short Pl[64 * 168];      // P (bf16 bits), cols 144..159 zeroed
  __shared__ __align__(16) short Vt[128 * 168];     // V^T [dd][kk^swz], rows 120..127 zero
  const float scale = 0.18257418583505536f;  // 30^-0.5
  int blk = blockIdx.x;
  int hh = blk % 6; int wid = blk / 6;
  int wj = wid & 15; int wi = (wid >> 4) & 15; int b = wid >> 8;
  int tid = threadIdx.x;
  int wave = tid >> 6, lane = tid & 63;
  int fm = lane & 15, quad = lane >> 4;
  const unsigned int* qu = (const unsigned int*)q;
  const unsigned int* ku = (const unsigned int*)k;
  const unsigned int* vu = (const unsigned int*)v;
  int hh15 = hh * 15, hh60 = hh * 60;

  // ---- phase 0: kv-position token table (one div/mod per position per block) ----
  if (tid < 144) {
    int ky = tid / 12, kx = tid % 12;
    int gy = wi * 8 - 4 + ky, gx = wj * 8 - 4 + kx;
    tokl[tid] = (gy >= 0 && gy < 128 && gx >= 0 && gx < 128)
              ? (short)(b * 16384 + gy * 128 + gx) : (short)-1;
  }
  __syncthreads();

  // ---- phase 1: V staging (vectorized; overlaps QK below). 10 passes cover
  //      kk 0..159 (144..159 -> zeros) x all 128 dd rows (120..127 -> zeros). ----
  {
    int kg = tid & 15, oct = tid >> 4;              // kk offset / dd-oct
    int colx = (oct & 1) << 4;                      // swizzle: col ^= (dd&8)<<1
    #pragma unroll
    for (int p = 0; p < 10; p++) {
      int kk = p * 16 + kg;
      int t = (kk < 144) ? (int)tokl[kk] : -1;
      U8 vv; vv.u = make_uint4(0, 0, 0, 0);
      if (oct < 15 && t >= 0)
        vv.u = *(const uint4*)(vu + (size_t)t * 360 + hh60 + oct * 4);
      short* wp = &Vt[oct * 8 * 168 + (kk ^ colx)];
      #pragma unroll
      for (int jj = 0; jj < 8; jj++) wp[jj * 168] = vv.h[jj];
    }
  }

  // ---- phase 2: QK MFMA with direct-from-global fragments ----
  f32x4 sacc[9] = {};
  {
    U8 qf;
    int r = wave * 16 + fm;
    int gy = wi * 8 + (r >> 3), gx = wj * 8 + (r & 7);
    const unsigned int* qp = qu + (size_t)(b * 16384 + gy * 128 + gx) * 90 + hh15 + quad * 4;
    qf.u.x = qp[0]; qf.u.y = qp[1]; qf.u.z = qp[2]; qf.u.w = qp[3];
    if (quad == 3) qf.u.w = 0;                      // zero pad channels 30,31
    #pragma unroll
    for (int nt = 0; nt < 9; nt++) {
      int t = (int)tokl[nt * 16 + fm];
      U8 kf; kf.u = make_uint4(0, 0, 0, 0);
      if (t >= 0) {
        const unsigned int* kp = ku + (size_t)t * 90 + hh15 + quad * 4;
        kf.u.x = kp[0]; kf.u.y = kp[1]; kf.u.z = kp[2]; kf.u.w = kp[3];
      }
      if (quad == 3) kf.u.w = 0;
      sacc[nt] = __builtin_amdgcn_mfma_f32_16x16x32_bf16(qf.h, kf.h, sacc[nt], 0, 0, 0);
    }
  }

  // ---- phase 3: softmax in registers ----
  float sv[9][4];
  const float* bias_g = bias_f + hh * 9216;
  {
    #pragma unroll
    for (int r = 0; r < 4; r++) {
      int row = wave * 16 + quad * 4 + r;
      #pragma unroll
      for (int nt = 0; nt < 9; nt++)
        sv[nt][r] = sacc[nt][r] * scale + bias_g[row * 144 + nt * 16 + fm];
    }
    float mr[4], sr[4];
    #pragma unroll
    for (int r = 0; r < 4; r++) {
      float m = sv[0][r];
      #pragma unroll
      for (int nt = 1; nt < 9; nt++) m = fmaxf(m, sv[nt][r]);
      #pragma unroll
      for (int sh = 1; sh < 16; sh <<= 1) m = fmaxf(m, __shfl_xor(m, sh));
      mr[r] = m;
    }
    #pragma unroll
    for (int r = 0; r < 4; r++) {
      float s = 0.f;
      #pragma unroll
      for (int nt = 0; nt < 9; nt++) { sv[nt][r] = __expf(sv[nt][r] - mr[r]); s += sv[nt][r]; }
      #pragma unroll
      for (int sh = 1; sh < 16; sh <<= 1) s += __shfl_xor(s, sh);
      sr[r] = 1.f / s;
    }
    #pragma unroll
    for (int r = 0; r < 4; r++)
      #pragma unroll
      for (int nt = 0; nt < 9; nt++) sv[nt][r] *= sr[r];
  }

  // ---- phase 4: write normalized P (own wave's rows only); zero pad cols 144..159 ----
  #pragma unroll
  for (int r = 0; r < 4; r++) {
    int row = wave * 16 + quad * 4 + r;
    #pragma unroll
    for (int nt = 0; nt < 9; nt++)
      Pl[row * 168 + nt * 16 + fm] = (short)__bfloat16_as_ushort(f2b(sv[nt][r]));
  }
  #pragma unroll
  for (int j2 = 0; j2 < 2; j2++) {
    int idx = lane * 2 + j2;                        // 0..127 -> 16 rows x 8 uints
    int row = wave * 16 + (idx >> 3);
    *(unsigned int*)&Pl[row * 168 + 144 + (idx & 7) * 2] = 0u;
  }
  __syncthreads();   // V staging complete (P rows are wave-local)

  // ---- phase 5: O = P @ Vt^T  (M=64, N=128, K=160) ----
  int sread = (fm & 8) << 1;
  bf16x8 pf[5];
  const short* prow = &Pl[(wave * 16 + fm) * 168];
  #pragma unroll
  for (int ks = 0; ks < 5; ks++) pf[ks] = *(const bf16x8*)&prow[ks * 32 + quad * 8];
  f32x4 oacc[8] = {};
  #pragma unroll
  for (int ks = 0; ks < 5; ks++) {
    #pragma unroll
    for (int nt = 0; nt < 8; nt++) {
      bf16x8 vf = *(const bf16x8*)&Vt[(nt * 16 + fm) * 168 + ((ks * 32 + quad * 8) ^ sread)];
      oacc[nt] = __builtin_amdgcn_mfma_f32_16x16x32_bf16(pf[ks], vf, oacc[nt], 0, 0, 0);
    }
  }
  #pragma unroll
  for (int nt = 0; nt < 8; nt++) {
    int col = nt * 16 + fm;
    if (col >= 120) continue;
    #pragma unroll
    for (int r = 0; r < 4; r++) {
      int row = wave * 16 + quad * 4 + r;
      int gy = wi * 8 + (row >> 3), gx = wj * 8 + (row & 7);
      xw[((size_t)b * 16384 + (size_t)gy * 128 + gx) * 720 + hh * 120 + col] = f2b(oacc[nt][r]);
    }
  }
}

// ---------------- IDWT: xw bf16 (.,720) -> xr bf16 stride 192 (zero-padded 180..191) ----
// 8 channels per thread, vector loads/stores. 131072 tokens x 24 chunks = 3145728 thr.
__global__ __launch_bounds__(256) void idwt_kernel(
    const bf16* __restrict__ xw, bf16* __restrict__ xr)
{
  int gid = blockIdx.x * 256 + threadIdx.x;
  int cu = gid % 24;
  int tokn = gid / 24;
  int c = cu * 8;
  bf16* op = xr + (size_t)tokn * 192 + c;
  uint4 outv = make_uint4(0, 0, 0, 0);
  if (c < 184) {
    int x2 = tokn & 255, y2 = (tokn >> 8) & 255, bb = tokn >> 16;
    int ii = y2 >> 1, jj = x2 >> 1, py = y2 & 1, px = x2 & 1;
    const unsigned short* p = (const unsigned short*)xw
        + ((size_t)bb * 16384 + (size_t)ii * 128 + jj) * 720 + c;
    union QW { uint4 v; uint2 u[2]; unsigned short s[8]; } a_, b_, c_, d_, o_;
    a_.u[0] = *(const uint2*)(p);        a_.u[1] = *(const uint2*)(p + 4);
    b_.u[0] = *(const uint2*)(p + 180);  b_.u[1] = *(const uint2*)(p + 184);
    c_.u[0] = *(const uint2*)(p + 360);  c_.u[1] = *(const uint2*)(p + 364);
    d_.u[0] = *(const uint2*)(p + 540);  d_.u[1] = *(const uint2*)(p + 544);
    #pragma unroll
    for (int t = 0; t < 8; t++) {
      float ll = bfu(a_.s[t]), lh = bfu(b_.s[t]), hl = bfu(c_.s[t]), hv = bfu(d_.s[t]);
      float r;
      if (py == 0) r = (px == 0) ? (ll - lh - hl + hv) : (ll - lh + hl - hv);
      else         r = (px == 0) ? (ll + lh - hl - hv) : (ll + lh + hl + hv);
      o_.s[t] = (c + t < 180) ? __bfloat16_as_ushort(f2b(r * 0.5f)) : (unsigned short)0;
    }
    outv = o_.v;
  }
  *(uint4*)op = outv;
}

extern "C" void kernel_launch(void* const* d_in, const int* in_sizes, int n_in,
                              void* d_out, int out_size, void* d_ws, size_t ws_size,
                              hipStream_t stream) {
  (void)in_sizes; (void)n_in; (void)out_size; (void)ws_size;
  const float* x      = (const float*)d_in[0];
  const int*   rpi    = (const int*)  d_in[2];
  const float* n1w    = (const float*)d_in[5];
  const float* n1b    = (const float*)d_in[6];
  const float* q_w    = (const float*)d_in[9];
  const float* q_b    = (const float*)d_in[10];
  const float* k_w    = (const float*)d_in[11];
  const float* k_b    = (const float*)d_in[12];
  const float* v_w    = (const float*)d_in[13];
  const float* v_b    = (const float*)d_in[14];
  const float* rpb    = (const float*)d_in[15];
  const float* proj_w = (const float*)d_in[16];
  const float* proj_b = (const float*)d_in[17];
  const float* n2w    = (const float*)d_in[18];
  const float* n2b    = (const float*)d_in[19];
  const float* fc1_w  = (const float*)d_in[20];
  const float* fc1_b  = (const float*)d_in[21];
  const float* fc2_w  = (const float*)d_in[22];
  const float* fc2_b  = (const float*)d_in[23];
  float* out = (float*)d_out;

  // ---- workspace layout (bf16 elements) ----
  bf16* xd  = (bf16*)d_ws;                  // 32768 x 720   (reused: xw, then yb)
  bf16* qb  = xd + 23592960;                // 32768 x 180
  bf16* kb  = qb + 5898240;                 // 32768 x 180
  bf16* vb  = kb + 5898240;                 // 32768 x 720
  bf16* x1  = vb + 23592960;                // 131072 x 180
  bf16* hb  = x1 + 23592960;                // 131072 x 360
  bf16* wts = hb + 47185920;
  bf16* qwt  = wts;                         // 180 x 736
  bf16* kwt  = qwt + 132480;                // 180 x 736
  bf16* vwt  = kwt + 132480;                // 720 x 736
  bf16* pwt  = vwt + 529920;                // 180 x 192
  bf16* f1wt = pwt + 34560;                 // 360 x 192
  bf16* f2wt = f1wt + 69120;                // 180 x 384
  float* bias_f = (float*)(f2wt + 69120);   // 6 x 64 x 144 fp32
  bf16* xw = xd;
  bf16* xr = qb + 10223616;                 // 131072 x 192 (tail of q/k/v region)
  bf16* yb = xd;

  convert_wt_kernel<<<518,  256, 0, stream>>>(q_w,    qwt,  720, 180, 736);
  convert_wt_kernel<<<518,  256, 0, stream>>>(k_w,    kwt,  720, 180, 736);
  convert_wt_kernel<<<2071, 256, 0, stream>>>(v_w,    vwt,  720, 720, 736);
  convert_wt_kernel<<<135,  256, 0, stream>>>(proj_w, pwt,  180, 180, 192);
  convert_wt_kernel<<<270,  256, 0, stream>>>(fc1_w,  f1wt, 180, 360, 192);
  convert_wt_kernel<<<270,  256, 0, stream>>>(fc2_w,  f2wt, 360, 180, 384);
  bias_pre_kernel<<<216, 256, 0, stream>>>(rpi, rpb, bias_f);

  ln_dwt_kernel<<<32768, 256, 0, stream>>>(x, n1w, n1b, xd);
  gemm_mfma<0, float, bf16><<<dim3(256, 3),  256, 0, stream>>>(xd, qwt, q_b, nullptr, qb, 180, 720, 720, 736, 180, 0);
  gemm_mfma<0, float, bf16><<<dim3(256, 3),  256, 0, stream>>>(xd, kwt, k_b, nullptr, kb, 180, 720, 720, 736, 180, 0);
  gemm_mfma<0, float, bf16><<<dim3(256, 12), 256, 0, stream>>>(xd, vwt, v_b, nullptr, vb, 720, 720, 720, 736, 720, 0);
  attn_kernel<<<3072, 256, 0, stream>>>(qb, kb, vb, bias_f, xw);
  idwt_kernel<<<12288, 256, 0, stream>>>(xw, xr);
  gemm_mfma<1, float, bf16><<<dim3(1024, 3), 256, 0, stream>>>(xr, pwt, proj_b, x, x1, 180, 192, 192, 192, 180, 180);
  ln_kernel<<<32768, 256, 0, stream>>>(x1, n2w, n2b, yb);
  gemm_mfma<2, float, bf16><<<dim3(1024, 6), 256, 0, stream>>>(yb, f1wt, fc1_b, nullptr, hb, 360, 192, 192, 192, 360, 0);
  gemm_mfma<1, bf16, float><<<dim3(1024, 3), 256, 0, stream>>>(hb, f2wt, fc2_b, x1, out, 180, 360, 360, 384, 180, 180);
}

// Round 2
// 729.539 us; speedup vs baseline: 1.2952x; 1.0648x over previous
//
#include <hip/hip_runtime.h>
#include <hip/hip_bf16.h>
#include <stdint.h>

using bf16 = __hip_bfloat16;
typedef __attribute__((ext_vector_type(8))) short bf16x8;
typedef __attribute__((ext_vector_type(4))) float f32x4;

union U8 { uint4 u; bf16x8 h; };

static __device__ __forceinline__ float b2f(bf16 v) { return __bfloat162float(v); }
static __device__ __forceinline__ bf16  f2b(float v) { return __float2bfloat16(v); }
static __device__ __forceinline__ float toF(float v) { return v; }
static __device__ __forceinline__ float toF(bf16 v)  { return __bfloat162float(v); }
static __device__ __forceinline__ void stF(float* p, float v) { *p = v; }
static __device__ __forceinline__ void stF(bf16* p,  float v) { *p = f2b(v); }
static __device__ __forceinline__ float bfu(unsigned short x) {
  union { unsigned int i; float f; } z; z.i = ((unsigned int)x) << 16; return z.f;
}

// ---------------- weight convert: w[k][n] fp32 -> wt[n][k] bf16, k zero-padded to Kp ----
__global__ __launch_bounds__(256) void convert_wt_kernel(
    const float* __restrict__ w, bf16* __restrict__ wt, int K, int N, int Kp)
{
  int idx = blockIdx.x * 256 + threadIdx.x;
  if (idx >= N * Kp) return;
  int n = idx / Kp, k = idx % Kp;
  float v = (k < K) ? w[(size_t)k * N + n] : 0.f;
  wt[idx] = f2b(v);
}

// ---------------- bias concat: [q_b | k_b | v_b] -> 1080 floats ------------------------
__global__ __launch_bounds__(256) void concat_bias_kernel(
    const float* __restrict__ qb, const float* __restrict__ kb,
    const float* __restrict__ vb, float* __restrict__ o)
{
  int i = blockIdx.x * 256 + threadIdx.x;
  if (i >= 1080) return;
  o[i] = (i < 180) ? qb[i] : (i < 360) ? kb[i - 180] : vb[i - 360];
}

// ---------------- bias precompute: bias_f[hh][r][kk] = rpb[rpi[r,kk]*6+hh] --------------
__global__ __launch_bounds__(256) void bias_pre_kernel(
    const int* __restrict__ rpi, const float* __restrict__ rpb, float* __restrict__ bias_f)
{
  int e = blockIdx.x * 256 + threadIdx.x;
  if (e >= 6 * 64 * 144) return;
  int hh = e / 9216, rk = e % 9216;
  bias_f[e] = rpb[rpi[rk] * 6 + hh];
}

// ---------------- LN1 + DWT: x fp32 (2,256,256,180) -> xd bf16 (2,128,128,720) ----------
__global__ __launch_bounds__(256) void ln_dwt_kernel(
    const float* __restrict__ x, const float* __restrict__ w, const float* __restrict__ bia,
    bf16* __restrict__ xd)
{
  __shared__ float nrm[4][180];
  int blk = blockIdx.x;
  int j = blk & 127; int i = (blk >> 7) & 127; int b = blk >> 14;
  int wave = threadIdx.x >> 6, lane = threadIdx.x & 63;
  int ty = wave >> 1, tx = wave & 1;
  size_t tok = (size_t)b * 65536 + (size_t)(2 * i + ty) * 256 + (size_t)(2 * j + tx);
  const float* xp = x + tok * 180;
  float v0 = xp[lane];
  float v1 = xp[lane + 64];
  float v2 = (lane < 52) ? xp[lane + 128] : 0.f;
  float s = v0 + v1 + v2, ss = v0 * v0 + v1 * v1 + v2 * v2;
  #pragma unroll
  for (int m = 32; m; m >>= 1) { s += __shfl_xor(s, m); ss += __shfl_xor(ss, m); }
  float mu = s * (1.f / 180.f);
  float rstd = rsqrtf(ss * (1.f / 180.f) - mu * mu + 1e-5f);
  nrm[wave][lane]      = (v0 - mu) * rstd * w[lane]      + bia[lane];
  nrm[wave][lane + 64] = (v1 - mu) * rstd * w[lane + 64] + bia[lane + 64];
  if (lane < 52)
    nrm[wave][lane + 128] = (v2 - mu) * rstd * w[lane + 128] + bia[lane + 128];
  __syncthreads();
  bf16* op = xd + (size_t)blk * 720;
  for (int o = threadIdx.x; o < 720; o += 256) {
    int g = o / 180, c = o % 180;
    float a = nrm[0][c], bb = nrm[1][c], cc = nrm[2][c], dd = nrm[3][c];
    float r = (g == 0) ? (a + bb + cc + dd)
            : (g == 1) ? (-a - bb + cc + dd)
            : (g == 2) ? (-a + bb - cc + dd)
                       : (a - bb - cc + dd);
    op[o] = f2b(r * 0.5f);
  }
}

// ---------------- plain LN: x1 bf16 (131072,180) -> y bf16 stride 192 (zero-padded) -----
__global__ __launch_bounds__(256) void ln_kernel(
    const bf16* __restrict__ x, const float* __restrict__ w, const float* __restrict__ bia,
    bf16* __restrict__ y)
{
  int wave = threadIdx.x >> 6, lane = threadIdx.x & 63;
  size_t tok = (size_t)blockIdx.x * 4 + wave;
  const bf16* xp = x + tok * 180;
  float v0 = b2f(xp[lane]);
  float v1 = b2f(xp[lane + 64]);
  float v2 = (lane < 52) ? b2f(xp[lane + 128]) : 0.f;
  float s = v0 + v1 + v2, ss = v0 * v0 + v1 * v1 + v2 * v2;
  #pragma unroll
  for (int m = 32; m; m >>= 1) { s += __shfl_xor(s, m); ss += __shfl_xor(ss, m); }
  float mu = s * (1.f / 180.f);
  float rstd = rsqrtf(ss * (1.f / 180.f) - mu * mu + 1e-5f);
  bf16* yp = y + tok * 192;
  yp[lane]      = f2b((v0 - mu) * rstd * w[lane]      + bia[lane]);
  yp[lane + 64] = f2b((v1 - mu) * rstd * w[lane + 64] + bia[lane + 64]);
  if (lane < 52)
    yp[lane + 128] = f2b((v2 - mu) * rstd * w[lane + 128] + bia[lane + 128]);
  else
    yp[lane + 128] = f2b(0.f);
}

// ---------------- MFMA GEMM: out = ep(A@Wt^T + bias [, res]) ----------------------------
// Block tile 128 x 192, waves 2x2 (per-wave 64x96, acc[4][6]). Prefetch next K-tile
// during MFMA phase. grid.y slices of 192 cols.
template <int EP, typename TRes, typename TOut>
__global__ __launch_bounds__(256) void gemm_mfma(
    const bf16* __restrict__ A, const bf16* __restrict__ Wt,
    const float* __restrict__ bias, const TRes* __restrict__ res,
    TOut* __restrict__ out, int N, int KlimA, int lda, int Kp, int ldout, int ldres)
{
  __shared__ __align__(16) short Al[128 * 32];
  __shared__ __align__(16) short Bl[192 * 32];
  int tid = threadIdx.x;
  int wave = tid >> 6, lane = tid & 63;
  int wy = wave >> 1, wx = wave & 1;
  int m0 = blockIdx.x * 128, n0 = blockIdx.y * 192;

  f32x4 acc[4][6] = {};

  int ar0 = tid >> 2;                 // 0..63
  int ac  = (tid & 3) * 8;            // 0,8,16,24
  const uint4* ga0 = (const uint4*)(A + (size_t)(m0 + ar0) * lda + ac);
  const uint4* ga1 = (const uint4*)(A + (size_t)(m0 + 64 + ar0) * lda + ac);
  int br0 = n0 + ar0, br1 = n0 + ar0 + 64, br2 = n0 + ar0 + 128;
  bool bv0 = br0 < N, bv1 = br1 < N, bv2 = br2 < N;
  const uint4* gb0 = (const uint4*)(Wt + (size_t)(bv0 ? br0 : 0) * Kp + ac);
  const uint4* gb1 = (const uint4*)(Wt + (size_t)(bv1 ? br1 : 0) * Kp + ac);
  const uint4* gb2 = (const uint4*)(Wt + (size_t)(bv2 ? br2 : 0) * Kp + ac);

  int fm = lane & 15, quad = lane >> 4;
  const short* afp = &Al[(wy * 64 + fm) * 32 + quad * 8];
  const short* bfp = &Bl[(wx * 96 + fm) * 32 + quad * 8];

  const uint4 Z = make_uint4(0, 0, 0, 0);
  uint4 za, zb, zc0, zc1, zc2;
  {
    bool av = ac < KlimA;
    za  = av ? ga0[0] : Z;
    zb  = av ? ga1[0] : Z;
    zc0 = bv0 ? gb0[0] : Z;
    zc1 = bv1 ? gb1[0] : Z;
    zc2 = bv2 ? gb2[0] : Z;
  }

  for (int k0 = 0; k0 < Kp; k0 += 32) {
    __syncthreads();
    *(uint4*)&Al[tid * 8]        = za;
    *(uint4*)&Al[2048 + tid * 8] = zb;
    *(uint4*)&Bl[tid * 8]        = zc0;
    *(uint4*)&Bl[2048 + tid * 8] = zc1;
    *(uint4*)&Bl[4096 + tid * 8] = zc2;
    __syncthreads();

    int kn = k0 + 32;
    if (kn < Kp) {
      bool av = (kn + ac) < KlimA;
      za  = av ? ga0[kn / 8] : Z;
      zb  = av ? ga1[kn / 8] : Z;
      zc0 = bv0 ? gb0[kn / 8] : Z;
      zc1 = bv1 ? gb1[kn / 8] : Z;
      zc2 = bv2 ? gb2[kn / 8] : Z;
    }

    bf16x8 af0 = *(const bf16x8*)(afp);
    bf16x8 af1 = *(const bf16x8*)(afp + 16 * 32);
    bf16x8 af2 = *(const bf16x8*)(afp + 32 * 32);
    bf16x8 af3 = *(const bf16x8*)(afp + 48 * 32);
    #pragma unroll
    for (int nt = 0; nt < 6; nt++) {
      bf16x8 bfr = *(const bf16x8*)(bfp + nt * 16 * 32);
      acc[0][nt] = __builtin_amdgcn_mfma_f32_16x16x32_bf16(af0, bfr, acc[0][nt], 0, 0, 0);
      acc[1][nt] = __builtin_amdgcn_mfma_f32_16x16x32_bf16(af1, bfr, acc[1][nt], 0, 0, 0);
      acc[2][nt] = __builtin_amdgcn_mfma_f32_16x16x32_bf16(af2, bfr, acc[2][nt], 0, 0, 0);
      acc[3][nt] = __builtin_amdgcn_mfma_f32_16x16x32_bf16(af3, bfr, acc[3][nt], 0, 0, 0);
    }
  }

  #pragma unroll
  for (int nt = 0; nt < 6; nt++) {
    int col = n0 + wx * 96 + nt * 16 + fm;
    if (col >= N) continue;
    float bv = bias[col];
    #pragma unroll
    for (int mt = 0; mt < 4; mt++) {
      int row0 = m0 + wy * 64 + mt * 16 + quad * 4;
      #pragma unroll
      for (int r = 0; r < 4; r++) {
        int row = row0 + r;
        float v = acc[mt][nt][r] + bv;
        if constexpr (EP == 1) v += toF(res[(size_t)row * ldres + col]);
        if constexpr (EP == 2) v = 0.5f * v * (1.f + erff(v * 0.70710678118654752f));
        stF(&out[(size_t)row * ldout + col], v);
      }
    }
  }
}

// ---------------- MFMA attention: one block per (window, head) --------------------------
// qkv: bf16 fused (32768 x 1080): q cols 0..179, k 180..359, v 360..1079.
// xw out bf16 stride 720; bias_f: [6][64][144]
__global__ __launch_bounds__(256) void attn_kernel(
    const bf16* __restrict__ qkv, const float* __restrict__ bias_f, bf16* __restrict__ xw)
{
  __shared__ short tokl[160];                       // 144 used; -1 = OOB
  __shared__ __align__(16) short Pl[64 * 168];      // P (bf16 bits), cols 144..159 zeroed
  __shared__ __align__(16) short Vt[128 * 168];     // V^T [dd][kk^swz], rows 120..127 zero
  const float scale = 0.18257418583505536f;  // 30^-0.5
  int blk = blockIdx.x;
  int hh = blk % 6; int wid = blk / 6;
  int wj = wid & 15; int wi = (wid >> 4) & 15; int b = wid >> 8;
  int tid = threadIdx.x;
  int wave = tid >> 6, lane = tid & 63;
  int fm = lane & 15, quad = lane >> 4;
  const unsigned int* qkvu = (const unsigned int*)qkv;   // row stride 540 uints
  int hh15 = hh * 15, hh60 = hh * 60;

  // ---- phase 0: kv-position token table ----
  if (tid < 144) {
    int ky = tid / 12, kx = tid % 12;
    int gy = wi * 8 - 4 + ky, gx = wj * 8 - 4 + kx;
    tokl[tid] = (gy >= 0 && gy < 128 && gx >= 0 && gx < 128)
              ? (short)(b * 16384 + gy * 128 + gx) : (short)-1;
  }
  __syncthreads();

  // ---- phase 1: V staging (vectorized). v row offset = 180 uints ----
  {
    int kg = tid & 15, oct = tid >> 4;              // kk offset / dd-oct
    int colx = (oct & 1) << 4;                      // swizzle: col ^= (dd&8)<<1
    #pragma unroll
    for (int p = 0; p < 10; p++) {
      int kk = p * 16 + kg;
      int t = (kk < 144) ? (int)tokl[kk] : -1;
      U8 vv; vv.u = make_uint4(0, 0, 0, 0);
      if (oct < 15 && t >= 0)
        vv.u = *(const uint4*)(qkvu + (size_t)t * 540 + 180 + hh60 + oct * 4);
      short* wp = &Vt[oct * 8 * 168 + (kk ^ colx)];
      #pragma unroll
      for (int jj = 0; jj < 8; jj++) wp[jj * 168] = vv.h[jj];
    }
  }

  // ---- phase 2: QK MFMA with direct-from-global fragments ----
  f32x4 sacc[9] = {};
  {
    U8 qf;
    int r = wave * 16 + fm;
    int gy = wi * 8 + (r >> 3), gx = wj * 8 + (r & 7);
    const unsigned int* qp = qkvu + (size_t)(b * 16384 + gy * 128 + gx) * 540 + hh15 + quad * 4;
    qf.u.x = qp[0]; qf.u.y = qp[1]; qf.u.z = qp[2]; qf.u.w = qp[3];
    if (quad == 3) qf.u.w = 0;                      // zero pad channels 30,31
    #pragma unroll
    for (int nt = 0; nt < 9; nt++) {
      int t = (int)tokl[nt * 16 + fm];
      U8 kf; kf.u = make_uint4(0, 0, 0, 0);
      if (t >= 0) {
        const unsigned int* kp = qkvu + (size_t)t * 540 + 90 + hh15 + quad * 4;
        kf.u.x = kp[0]; kf.u.y = kp[1]; kf.u.z = kp[2]; kf.u.w = kp[3];
      }
      if (quad == 3) kf.u.w = 0;
      sacc[nt] = __builtin_amdgcn_mfma_f32_16x16x32_bf16(qf.h, kf.h, sacc[nt], 0, 0, 0);
    }
  }

  // ---- phase 3: softmax in registers ----
  float sv[9][4];
  const float* bias_g = bias_f + hh * 9216;
  {
    #pragma unroll
    for (int r = 0; r < 4; r++) {
      int row = wave * 16 + quad * 4 + r;
      #pragma unroll
      for (int nt = 0; nt < 9; nt++)
        sv[nt][r] = sacc[nt][r] * scale + bias_g[row * 144 + nt * 16 + fm];
    }
    float mr[4], sr[4];
    #pragma unroll
    for (int r = 0; r < 4; r++) {
      float m = sv[0][r];
      #pragma unroll
      for (int nt = 1; nt < 9; nt++) m = fmaxf(m, sv[nt][r]);
      #pragma unroll
      for (int sh = 1; sh < 16; sh <<= 1) m = fmaxf(m, __shfl_xor(m, sh));
      mr[r] = m;
    }
    #pragma unroll
    for (int r = 0; r < 4; r++) {
      float s = 0.f;
      #pragma unroll
      for (int nt = 0; nt < 9; nt++) { sv[nt][r] = __expf(sv[nt][r] - mr[r]); s += sv[nt][r]; }
      #pragma unroll
      for (int sh = 1; sh < 16; sh <<= 1) s += __shfl_xor(s, sh);
      sr[r] = 1.f / s;
    }
    #pragma unroll
    for (int r = 0; r < 4; r++)
      #pragma unroll
      for (int nt = 0; nt < 9; nt++) sv[nt][r] *= sr[r];
  }

  // ---- phase 4: write normalized P; zero pad cols 144..159 ----
  #pragma unroll
  for (int r = 0; r < 4; r++) {
    int row = wave * 16 + quad * 4 + r;
    #pragma unroll
    for (int nt = 0; nt < 9; nt++)
      Pl[row * 168 + nt * 16 + fm] = (short)__bfloat16_as_ushort(f2b(sv[nt][r]));
  }
  #pragma unroll
  for (int j2 = 0; j2 < 2; j2++) {
    int idx = lane * 2 + j2;
    int row = wave * 16 + (idx >> 3);
    *(unsigned int*)&Pl[row * 168 + 144 + (idx & 7) * 2] = 0u;
  }
  __syncthreads();   // V staging complete (P rows are wave-local)

  // ---- phase 5: O = P @ Vt^T  (M=64, N=128, K=160) ----
  int sread = (fm & 8) << 1;
  bf16x8 pf[5];
  const short* prow = &Pl[(wave * 16 + fm) * 168];
  #pragma unroll
  for (int ks = 0; ks < 5; ks++) pf[ks] = *(const bf16x8*)&prow[ks * 32 + quad * 8];
  f32x4 oacc[8] = {};
  #pragma unroll
  for (int ks = 0; ks < 5; ks++) {
    #pragma unroll
    for (int nt = 0; nt < 8; nt++) {
      bf16x8 vf = *(const bf16x8*)&Vt[(nt * 16 + fm) * 168 + ((ks * 32 + quad * 8) ^ sread)];
      oacc[nt] = __builtin_amdgcn_mfma_f32_16x16x32_bf16(pf[ks], vf, oacc[nt], 0, 0, 0);
    }
  }
  #pragma unroll
  for (int nt = 0; nt < 8; nt++) {
    int col = nt * 16 + fm;
    if (col >= 120) continue;
    #pragma unroll
    for (int r = 0; r < 4; r++) {
      int row = wave * 16 + quad * 4 + r;
      int gy = wi * 8 + (row >> 3), gx = wj * 8 + (row & 7);
      xw[((size_t)b * 16384 + (size_t)gy * 128 + gx) * 720 + hh * 120 + col] = f2b(oacc[nt][r]);
    }
  }
}

// ---------------- IDWT: xw bf16 (.,720) -> xr bf16 stride 192 (zero-padded 180..191) ----
__global__ __launch_bounds__(256) void idwt_kernel(
    const bf16* __restrict__ xw, bf16* __restrict__ xr)
{
  int gid = blockIdx.x * 256 + threadIdx.x;
  int cu = gid % 24;
  int tokn = gid / 24;
  int c = cu * 8;
  bf16* op = xr + (size_t)tokn * 192 + c;
  uint4 outv = make_uint4(0, 0, 0, 0);
  if (c < 184) {
    int x2 = tokn & 255, y2 = (tokn >> 8) & 255, bb = tokn >> 16;
    int ii = y2 >> 1, jj = x2 >> 1, py = y2 & 1, px = x2 & 1;
    const unsigned short* p = (const unsigned short*)xw
        + ((size_t)bb * 16384 + (size_t)ii * 128 + jj) * 720 + c;
    union QW { uint4 v; uint2 u[2]; unsigned short s[8]; } a_, b_, c_, d_, o_;
    a_.u[0] = *(const uint2*)(p);        a_.u[1] = *(const uint2*)(p + 4);
    b_.u[0] = *(const uint2*)(p + 180);  b_.u[1] = *(const uint2*)(p + 184);
    c_.u[0] = *(const uint2*)(p + 360);  c_.u[1] = *(const uint2*)(p + 364);
    d_.u[0] = *(const uint2*)(p + 540);  d_.u[1] = *(const uint2*)(p + 544);
    #pragma unroll
    for (int t = 0; t < 8; t++) {
      float ll = bfu(a_.s[t]), lh = bfu(b_.s[t]), hl = bfu(c_.s[t]), hv = bfu(d_.s[t]);
      float r;
      if (py == 0) r = (px == 0) ? (ll - lh - hl + hv) : (ll - lh + hl - hv);
      else         r = (px == 0) ? (ll + lh - hl - hv) : (ll + lh + hl + hv);
      o_.s[t] = (c + t < 180) ? __bfloat16_as_ushort(f2b(r * 0.5f)) : (unsigned short)0;
    }
    outv = o_.v;
  }
  *(uint4*)op = outv;
}

extern "C" void kernel_launch(void* const* d_in, const int* in_sizes, int n_in,
                              void* d_out, int out_size, void* d_ws, size_t ws_size,
                              hipStream_t stream) {
  (void)in_sizes; (void)n_in; (void)out_size; (void)ws_size;
  const float* x      = (const float*)d_in[0];
  const int*   rpi    = (const int*)  d_in[2];
  const float* n1w    = (const float*)d_in[5];
  const float* n1b    = (const float*)d_in[6];
  const float* q_w    = (const float*)d_in[9];
  const float* q_b    = (const float*)d_in[10];
  const float* k_w    = (const float*)d_in[11];
  const float* k_b    = (const float*)d_in[12];
  const float* v_w    = (const float*)d_in[13];
  const float* v_b    = (const float*)d_in[14];
  const float* rpb    = (const float*)d_in[15];
  const float* proj_w = (const float*)d_in[16];
  const float* proj_b = (const float*)d_in[17];
  const float* n2w    = (const float*)d_in[18];
  const float* n2b    = (const float*)d_in[19];
  const float* fc1_w  = (const float*)d_in[20];
  const float* fc1_b  = (const float*)d_in[21];
  const float* fc2_w  = (const float*)d_in[22];
  const float* fc2_b  = (const float*)d_in[23];
  float* out = (float*)d_out;

  // ---- workspace layout (bf16 elements) ----
  bf16* xd  = (bf16*)d_ws;                  // 32768 x 720   (reused: xw, then yb)
  bf16* qkv = xd + 23592960;                // 32768 x 1080  (q|k|v fused)
  bf16* x1  = qkv + 35389440;               // 131072 x 180
  bf16* hb  = x1 + 23592960;                // 131072 x 360
  bf16* wts = hb + 47185920;
  bf16* qkvwt = wts;                        // 1080 x 736 (q rows 0..179, k 180..359, v 360..1079)
  bf16* pwt  = qkvwt + 794880;              // 180 x 192
  bf16* f1wt = pwt + 34560;                 // 360 x 192
  bf16* f2wt = f1wt + 69120;                // 180 x 384
  float* bias_f = (float*)(f2wt + 69120);   // 6 x 64 x 144 fp32
  float* qkv_b  = bias_f + 55296;           // 1080 fp32
  bf16* xw = xd;
  bf16* xr = qkv + 10223616;                // 131072 x 192 (tail of qkv region)
  bf16* yb = xd;

  convert_wt_kernel<<<518,  256, 0, stream>>>(q_w,    qkvwt,          720, 180, 736);
  convert_wt_kernel<<<518,  256, 0, stream>>>(k_w,    qkvwt + 132480, 720, 180, 736);
  convert_wt_kernel<<<2071, 256, 0, stream>>>(v_w,    qkvwt + 264960, 720, 720, 736);
  convert_wt_kernel<<<135,  256, 0, stream>>>(proj_w, pwt,  180, 180, 192);
  convert_wt_kernel<<<270,  256, 0, stream>>>(fc1_w,  f1wt, 180, 360, 192);
  convert_wt_kernel<<<270,  256, 0, stream>>>(fc2_w,  f2wt, 360, 180, 384);
  concat_bias_kernel<<<5, 256, 0, stream>>>(q_b, k_b, v_b, qkv_b);
  bias_pre_kernel<<<216, 256, 0, stream>>>(rpi, rpb, bias_f);

  ln_dwt_kernel<<<32768, 256, 0, stream>>>(x, n1w, n1b, xd);
  gemm_mfma<0, float, bf16><<<dim3(256, 6),  256, 0, stream>>>(xd, qkvwt, qkv_b, nullptr, qkv, 1080, 720, 720, 736, 1080, 0);
  attn_kernel<<<3072, 256, 0, stream>>>(qkv, bias_f, xw);
  idwt_kernel<<<12288, 256, 0, stream>>>(xw, xr);
  gemm_mfma<1, float, bf16><<<dim3(1024, 1), 256, 0, stream>>>(xr, pwt, proj_b, x, x1, 180, 192, 192, 192, 180, 180);
  ln_kernel<<<32768, 256, 0, stream>>>(x1, n2w, n2b, yb);
  gemm_mfma<2, float, bf16><<<dim3(1024, 2), 256, 0, stream>>>(yb, f1wt, fc1_b, nullptr, hb, 360, 192, 192, 192, 360, 0);
  gemm_mfma<1, bf16, float><<<dim3(1024, 1), 256, 0, stream>>>(hb, f2wt, fc2_b, x1, out, 180, 360, 360, 384, 180, 180);
}